// Round 5
// baseline (651.015 us; speedup 1.0000x reference)
//
#include <hip/hip_runtime.h>
#include <stdint.h>

// BiDAF co-attention, B=8, L=4096, D=1024, M=2. All FP32.
// Compute/streaming split pipeline:
//   kA1 : READ-ONLY pass over input (plain loads -> stays in Infinity Cache).
//         Per row: att dots -> w0 -> w0buf; online softmax-over-L stats/acc
//         -> per-block partials. No output stores, no rm registers.
//   kB  : 32 blocks combine 256 partials/batch -> normalized out2[b][d].
//   kA2 : WRITE-ONLY fill-like pass: re-reads input (L3-hit, NT loads),
//         writes all 4 segments contiguously (16KB/row, no holes) with NT
//         stores. No reductions, no LDS, minimal VGPR.
// HBM traffic: 134 MB read (pass 1) + ~537 MB write (+ ~12 MB partials);
// pass-2 input reads served by the 256 MB memory-side L3.

#define BB 8
#define LL 4096
#define DD 1024
#define NBLK1 2048         // kA1 blocks
#define BPB 256            // kA1 blocks per batch
#define RPB 16             // rows per kA1 block
#define RPW 4              // rows per wave (kA1)
#define NBLK2 4096         // kA2 blocks
#define RPB2 8             // rows per kA2 block

typedef float f32x4 __attribute__((ext_vector_type(4)));

static __device__ __forceinline__ f32x4 nt_load4(const float* p) {
    return __builtin_nontemporal_load((const f32x4*)p);
}
static __device__ __forceinline__ void nt_store4(float* p, f32x4 v) {
    __builtin_nontemporal_store(v, (f32x4*)p);
}
static __device__ __forceinline__ float hsum4(f32x4 v) {
    return (v.x + v.y) + (v.z + v.w);
}

// ---- kA1: read-only att + softmax-over-L stats. 2048 blocks, 4 rows/wave.
__global__ __launch_bounds__(256) void kA1(const float* __restrict__ input,
                                           const float* __restrict__ memory,
                                           const float* __restrict__ w_in,
                                           const float* __restrict__ w_mem,
                                           const float* __restrict__ ds,
                                           float* __restrict__ w0buf,
                                           float* __restrict__ pmax,
                                           float* __restrict__ pz,
                                           float* __restrict__ pacc) {
    int blk = blockIdx.x;          // 2048
    int b = blk >> 8, chunk = blk & 255;
    int t = threadIdx.x;
    int wave = t >> 6, lane = t & 63;

    // prolog: fold weights in-register; mdot via butterfly (no rm needed)
    f32x4 rc0[4], rc1[4], acc[4];
    float md0 = 0.f, md1 = 0.f;
    {
        const float* m0p = memory + (size_t)b * 2 * DD;
        const float* m1p = m0p + DD;
#pragma unroll
        for (int k = 0; k < 4; ++k) {
            int i = 4 * (lane + 64 * k);
            f32x4 m0 = *(const f32x4*)(m0p + i);
            f32x4 m1 = *(const f32x4*)(m1p + i);
            f32x4 wi = *(const f32x4*)(w_in + i);
            f32x4 dv = *(const f32x4*)(ds + i);
            f32x4 wm = *(const f32x4*)(w_mem + i);
            rc0[k] = wi + dv * m0;
            rc1[k] = wi + dv * m1;
            md0 += hsum4(m0 * wm);
            md1 += hsum4(m1 * wm);
            acc[k] = (f32x4)(0.f);
        }
        for (int off = 32; off; off >>= 1) {
            md0 += __shfl_xor(md0, off);
            md1 += __shfl_xor(md1, off);
        }
    }

    float lmax = -1e30f, zsum = 0.f;
    int l0 = chunk * RPB + wave * RPW;
    const float* inb = input + (size_t)b * LL * DD;
    for (int r = 0; r < RPW; ++r) {
        int l = l0 + r;
        const float* row = inb + (size_t)l * DD;   // plain loads: retain in caches
        f32x4 x[4];
#pragma unroll
        for (int k = 0; k < 4; ++k) x[k] = *(const f32x4*)(row + 4 * (lane + 64 * k));

        f32x4 s0 = x[0] * rc0[0], s1 = x[0] * rc1[0];
#pragma unroll
        for (int k = 1; k < 4; ++k) { s0 += x[k] * rc0[k]; s1 += x[k] * rc1[k]; }
        float a0 = hsum4(s0), a1 = hsum4(s1);
        for (int off = 32; off; off >>= 1) {
            a0 += __shfl_xor(a0, off);
            a1 += __shfl_xor(a1, off);
        }
        a0 += md0; a1 += md1;

        float w0 = 1.f / (1.f + __expf(a1 - a0));   // softmax over M=2
        if (lane == 0) w0buf[(size_t)b * LL + l] = w0;
        float ml = fmaxf(a0, a1);

        // online softmax over L (wave-uniform branch)
        float e;
        if (ml > lmax) {
            float s = __expf(lmax - ml);
            zsum *= s;
#pragma unroll
            for (int k = 0; k < 4; ++k) acc[k] *= s;
            lmax = ml;
            e = 1.f;
        } else {
            e = __expf(ml - lmax);
        }
        zsum += e;
#pragma unroll
        for (int k = 0; k < 4; ++k) acc[k] += e * x[k];
    }

    // block combine: conflict-free per-wave LDS slices
    __shared__ float swm[4], swz[4];
    __shared__ __align__(16) float swacc[4][DD];
    if (lane == 0) { swm[wave] = lmax; swz[wave] = zsum; }
    __syncthreads();
    float bmax = fmaxf(fmaxf(swm[0], swm[1]), fmaxf(swm[2], swm[3]));
    float f = __expf(lmax - bmax);
#pragma unroll
    for (int k = 0; k < 4; ++k) {
        *(f32x4*)(swacc[wave] + 4 * (lane + 64 * k)) = f * acc[k];
    }
    __syncthreads();
    {
        f32x4 s = *(const f32x4*)(swacc[0] + 4 * t) + *(const f32x4*)(swacc[1] + 4 * t)
                + *(const f32x4*)(swacc[2] + 4 * t) + *(const f32x4*)(swacc[3] + 4 * t);
        *(f32x4*)(pacc + (size_t)blk * DD + 4 * t) = s;
        if (t == 0) {
            float bz = 0.f;
#pragma unroll
            for (int w = 0; w < 4; ++w) bz += swz[w] * __expf(swm[w] - bmax);
            pmax[blk] = bmax;
            pz[blk]   = bz;
        }
    }
}

// ---- kB: 32 blocks (batch x 256-d slice) combine 256 partials/batch -> out2
__global__ __launch_bounds__(256) void kB(const float* __restrict__ pmax,
                                          const float* __restrict__ pz,
                                          const float* __restrict__ pacc,
                                          float* __restrict__ out2) {
    int bid = blockIdx.x;           // 32
    int b = bid >> 2, q = bid & 3;
    int t = threadIdx.x;
    int d = q * 256 + t;
    __shared__ float se[BPB];
    const float* pm  = pmax + b * BPB;
    const float* pzb = pz   + b * BPB;
    float m = -1e30f;
    for (int i = 0; i < BPB; ++i) m = fmaxf(m, pm[i]);     // broadcast loads
    se[t] = __expf(pm[t] - m);
    __syncthreads();
    float Z = 0.f;
    for (int i = 0; i < BPB; ++i) Z = fmaf(pzb[i], se[i], Z);
    float invZ = 1.f / Z;

    const float* P = pacc + (size_t)b * BPB * DD + d;
    float a = 0.f;
    for (int i = 0; i < BPB; ++i) a = fmaf(se[i], P[(size_t)i * DD], a);
    out2[(size_t)b * DD + d] = a * invZ;
}

// ---- kA2: fill-like writer. 4096 blocks x 8 rows; all 4 segments per row.
__global__ __launch_bounds__(256) void kA2(const float* __restrict__ input,
                                           const float* __restrict__ memory,
                                           const float* __restrict__ w0buf,
                                           const float* __restrict__ out2,
                                           float* __restrict__ out) {
    int bid = blockIdx.x;           // 4096
    int b = bid >> 9, chunk = bid & 511;
    int t = threadIdx.x;
    f32x4 m0 = *(const f32x4*)(memory + (size_t)b * 2 * DD + 4 * t);
    f32x4 m1 = *(const f32x4*)(memory + (size_t)b * 2 * DD + DD + 4 * t);
    f32x4 o2 = *(const f32x4*)(out2 + (size_t)b * DD + 4 * t);
    const float* w0b = w0buf + (size_t)b * LL + chunk * RPB2;
    const float* inb = input + (size_t)(b * LL + chunk * RPB2) * DD;
#pragma unroll 2
    for (int r = 0; r < RPB2; ++r) {
        float w0 = w0b[r];
        float w1 = 1.f - w0;
        f32x4 x = nt_load4(inb + (size_t)r * DD + 4 * t);   // L3-resident re-read
        f32x4 o1 = w0 * m0 + w1 * m1;
        float* orow = out + (size_t)(b * LL + chunk * RPB2 + r) * (4 * DD);
        nt_store4(orow + 4 * t, x);                  // seg0
        nt_store4(orow + DD + 4 * t, o1);            // seg1
        nt_store4(orow + 2 * DD + 4 * t, x * o1);    // seg2
        nt_store4(orow + 3 * DD + 4 * t, o2 * o1);   // seg3
    }
}

extern "C" void kernel_launch(void* const* d_in, const int* in_sizes, int n_in,
                              void* d_out, int out_size, void* d_ws, size_t ws_size,
                              hipStream_t stream) {
    const float* input  = (const float*)d_in[0];   // [8,4096,1024] fp32
    const float* memory = (const float*)d_in[1];   // [8,2,1024] fp32
    const float* w_in   = (const float*)d_in[2];   // [1024] fp32
    const float* w_mem  = (const float*)d_in[3];   // [1024] fp32
    const float* ds     = (const float*)d_in[4];   // [1024] fp32
    float* out = (float*)d_out;                    // [8,4096,4096] fp32

    // workspace (floats): w0buf 32768 | pmax 2048 | pz 2048 | out2 8192 | pacc 2M (~8.6 MB)
    float* ws    = (float*)d_ws;
    float* w0buf = ws;
    float* pmax  = ws + 32768;
    float* pz    = ws + 34816;
    float* out2  = ws + 36864;
    float* pacc  = ws + 45056;

    kA1<<<NBLK1, 256, 0, stream>>>(input, memory, w_in, w_mem, ds,
                                   w0buf, pmax, pz, pacc);
    kB <<<32,    256, 0, stream>>>(pmax, pz, pacc, out2);
    kA2<<<NBLK2, 256, 0, stream>>>(input, memory, w0buf, out2, out);
}